// Round 5
// baseline (11671.609 us; speedup 1.0000x reference)
//
#include <hip/hip_runtime.h>
#include <hip/hip_bf16.h>

typedef __attribute__((ext_vector_type(2))) _Float16 half2v;
typedef __attribute__((ext_vector_type(4))) _Float16 half4;
typedef __attribute__((ext_vector_type(8))) _Float16 half8;
typedef __attribute__((ext_vector_type(4))) float f32x4;
typedef __attribute__((ext_vector_type(2))) float f32x2;

#define T_ 512
#define B_ 256
#define I_ 64
#define H_ 512
#define BH (B_ * H_)
#define NKS0 36   // K = 64(x) + 512(h1)
#define NKS1 64   // K = 512(h1) + 512(h2)

// Wp[((cb*4+w)*NKS+ks)*256 + l*4 + i] = W[g = w*512 + cb*16 + (l&15)][k = ks*16 + (l>>4)*4 + i]
template<int NKS, int K0>
__global__ void pack_w(const float* __restrict__ Wih, const float* __restrict__ Whh,
                       _Float16* __restrict__ Wp) {
    int idx = blockIdx.x * 256 + threadIdx.x;
    int i  = idx & 3;
    int l  = (idx >> 2) & 63;
    int rest = idx >> 8;
    int ks = rest % NKS;
    int r  = rest / NKS;
    int w  = r & 3;
    int cb = r >> 2;
    int g  = w * H_ + cb * 16 + (l & 15);
    int k  = ks * 16 + ((l >> 4) << 2) + i;
    float v = (k < K0) ? Wih[(size_t)g * K0 + k] : Whh[(size_t)g * H_ + (k - K0)];
    Wp[idx] = (_Float16)v;
}

// ---- persistent LSTM: 256 blocks x 512 threads (1/CU guaranteed by LDS).
// Block bid: group g=bid>>5 (32 batch rows), col-block cb=bid&31 (16 hidden cols).
// Waves 0-3: layer0 gates i,f,g,o. Waves 4-7: layer1 gates. Shared staged tile.
// Iteration tt: layer0 computes h1[tt] (tt<T), layer1 computes h2[tt-1] (tt>=1).
__global__ __launch_bounds__(512, 2) void lstm_persistent(
    const float* __restrict__ x,
    const _Float16* __restrict__ Wp0, const _Float16* __restrict__ Wp1,
    const float* __restrict__ bih0, const float* __restrict__ bhh0,
    const float* __restrict__ bih1, const float* __restrict__ bhh1,
    _Float16* __restrict__ h1buf, _Float16* __restrict__ h2buf,
    unsigned* __restrict__ bar)
{
    const int bid = blockIdx.x;
    const int g = bid >> 5, cb = bid & 31;
    const int tid = threadIdx.x;
    const int w = tid >> 6, l = tid & 63;
    const int lr = l & 15, lk = l >> 4;
    const int R0 = g * 32, c0 = cb * 16;
    const int sw = (lr & 7) << 4;          // XOR swizzle for this lane's tile rows

    __shared__ __attribute__((aligned(16))) char smem[65536 + 2 * 9216];
    float* gA = (float*)(smem + 65536);          // [4][32][18]
    float* gB = gA + 4 * 32 * 18;

    unsigned* cnt = bar + g * 64;       // 256B per group
    unsigned* gen = cnt + 32;           // separate cacheline

    const int er = (tid >> 3) & 31;     // epilogue row 0..31
    const int ec = (tid & 7) << 1;      // epilogue col 0,2..14
    const bool lay1 = tid >= 256;

    // bias for this thread's epilogue slice
    float br[4][2];
    {
        const float* bi = lay1 ? bih1 : bih0;
        const float* bh = lay1 ? bhh1 : bhh0;
        #pragma unroll
        for (int q = 0; q < 4; ++q)
            #pragma unroll
            for (int cc = 0; cc < 2; ++cc) {
                int gc = q * H_ + c0 + ec + cc;
                br[q][cc] = bi[gc] + bh[gc];
            }
    }

    // resident weights (layer per wave-half)
    half4 breg0[NKS0];
    half4 breg1[NKS1];
    if (w < 4) {
        const _Float16* wb = Wp0 + ((size_t)(cb * 4 + w) * NKS0) * 256 + l * 4;
        #pragma unroll
        for (int ks = 0; ks < NKS0; ++ks) breg0[ks] = *(const half4*)(wb + ks * 256);
    } else {
        const _Float16* wb = Wp1 + ((size_t)(cb * 4 + (w - 4)) * NKS1) * 256 + l * 4;
        #pragma unroll
        for (int ks = 0; ks < NKS1; ++ks) breg1[ks] = *(const half4*)(wb + ks * 256);
    }

    f32x2 cstr = {0.f, 0.f};   // c1 (tid<256) or c2 (tid>=256) for (er, ec..ec+1)

    for (int tt = 0; tt <= T_; ++tt) {
        // x prefetch for this step (layer0 waves only; independent of barrier)
        f32x4 xr0[4], xr1[4];
        if (w < 4 && tt < T_) {
            const float* xa = x + (size_t)(R0 + lr) * (T_ * I_) + tt * I_ + lk * 4;
            const float* xb = x + (size_t)(R0 + 16 + lr) * (T_ * I_) + tt * I_ + lk * 4;
            #pragma unroll
            for (int ks = 0; ks < 4; ++ks) {
                xr0[ks] = *(const f32x4*)(xa + ks * 16);
                xr1[ks] = *(const f32x4*)(xb + ks * 16);
            }
        }

        // ---- wait for previous step's h to be globally visible ----
        if (tid == 0 && tt > 0) {
            while (__hip_atomic_load(gen, __ATOMIC_RELAXED, __HIP_MEMORY_SCOPE_AGENT) < (unsigned)tt)
                __builtin_amdgcn_s_sleep(2);
            __builtin_amdgcn_fence(__ATOMIC_ACQUIRE, "agent");
        }
        __syncthreads();

        // ---- stage tile = [ h1[tt-1] | h2[tt-2] ] for our 32 rows, XOR-swizzled ----
        {
            const _Float16* h1p = h1buf + ((tt + 1) & 1) * BH;
            const _Float16* h2p = h2buf + (tt & 1) * BH;
            #pragma unroll
            for (int it = 0; it < 8; ++it) {
                int cch = tid + it * 512;
                int row = cch >> 7, gr = cch & 127;
                const _Float16* src = (gr < 64)
                    ? h1p + (size_t)(R0 + row) * H_ + (gr << 3)
                    : h2p + (size_t)(R0 + row) * H_ + ((gr - 64) << 3);
                *(half8*)(smem + row * 2048 + ((gr ^ (row & 7)) << 4)) = *(const half8*)src;
            }
        }
        __syncthreads();

        // ---- MFMA + gate exchange ----
        if (w < 4) {
            if (tt < T_) {
                f32x4 acc0 = {0.f,0.f,0.f,0.f}, acc1 = {0.f,0.f,0.f,0.f};
                #pragma unroll
                for (int ks = 0; ks < 4; ++ks) {
                    half4 a0 = {(_Float16)xr0[ks][0], (_Float16)xr0[ks][1], (_Float16)xr0[ks][2], (_Float16)xr0[ks][3]};
                    half4 a1 = {(_Float16)xr1[ks][0], (_Float16)xr1[ks][1], (_Float16)xr1[ks][2], (_Float16)xr1[ks][3]};
                    acc0 = __builtin_amdgcn_mfma_f32_16x16x16f16(a0, breg0[ks], acc0, 0, 0, 0);
                    acc1 = __builtin_amdgcn_mfma_f32_16x16x16f16(a1, breg0[ks], acc1, 0, 0, 0);
                }
                #pragma unroll
                for (int ks = 4; ks < NKS0; ++ks) {
                    int cbyte = (ks - 4) * 32 + lk * 8;
                    half4 a0 = *(const half4*)(smem + lr * 2048 + (cbyte ^ sw));
                    half4 a1 = *(const half4*)(smem + (lr + 16) * 2048 + (cbyte ^ sw));
                    acc0 = __builtin_amdgcn_mfma_f32_16x16x16f16(a0, breg0[ks], acc0, 0, 0, 0);
                    acc1 = __builtin_amdgcn_mfma_f32_16x16x16f16(a1, breg0[ks], acc1, 0, 0, 0);
                }
                float* gb = gA + w * 576;
                #pragma unroll
                for (int r = 0; r < 4; ++r) {
                    gb[(lk * 4 + r) * 18 + lr]        = acc0[r];
                    gb[(16 + lk * 4 + r) * 18 + lr]   = acc1[r];
                }
            }
        } else {
            if (tt >= 1) {
                f32x4 acc0 = {0.f,0.f,0.f,0.f}, acc1 = {0.f,0.f,0.f,0.f};
                #pragma unroll
                for (int ks = 0; ks < NKS1; ++ks) {
                    int cbyte = ks * 32 + lk * 8;
                    half4 a0 = *(const half4*)(smem + lr * 2048 + (cbyte ^ sw));
                    half4 a1 = *(const half4*)(smem + (lr + 16) * 2048 + (cbyte ^ sw));
                    acc0 = __builtin_amdgcn_mfma_f32_16x16x16f16(a0, breg1[ks], acc0, 0, 0, 0);
                    acc1 = __builtin_amdgcn_mfma_f32_16x16x16f16(a1, breg1[ks], acc1, 0, 0, 0);
                }
                float* gb = gB + (w - 4) * 576;
                #pragma unroll
                for (int r = 0; r < 4; ++r) {
                    gb[(lk * 4 + r) * 18 + lr]        = acc0[r];
                    gb[(16 + lk * 4 + r) * 18 + lr]   = acc1[r];
                }
            }
        }
        __syncthreads();

        // ---- LSTM cell epilogue + h store ----
        bool act = lay1 ? (tt >= 1) : (tt < T_);
        if (act) {
            const float* gb = lay1 ? gB : gA;
            f32x2 gv[4];
            #pragma unroll
            for (int q = 0; q < 4; ++q) gv[q] = *(const f32x2*)&gb[q * 576 + er * 18 + ec];
            half2v hv;
            #pragma unroll
            for (int cc = 0; cc < 2; ++cc) {
                float gi = gv[0][cc] + br[0][cc];
                float gf = gv[1][cc] + br[1][cc];
                float gg = gv[2][cc] + br[2][cc];
                float go = gv[3][cc] + br[3][cc];
                float si = 1.f / (1.f + __expf(-gi));
                float sf = 1.f / (1.f + __expf(-gf));
                float tg = tanhf(gg);
                float so = 1.f / (1.f + __expf(-go));
                float cn = sf * cstr[cc] + si * tg;
                cstr[cc] = cn;
                hv[cc] = (_Float16)(so * tanhf(cn));
            }
            _Float16* dst = lay1 ? (h2buf + ((tt + 1) & 1) * BH)   // h2[tt-1]
                                 : (h1buf + (tt & 1) * BH);        // h1[tt]
            *(half2v*)&dst[(size_t)(R0 + er) * H_ + c0 + ec] = hv;
        }
        __syncthreads();   // per-wave vmcnt drained before barrier

        // ---- arrival: release h stores, count up, last sets gen ----
        if (tt < T_ && tid == 0) {
            unsigned prev = __hip_atomic_fetch_add(cnt, 1u, __ATOMIC_RELEASE, __HIP_MEMORY_SCOPE_AGENT);
            if (prev == (unsigned)tt * 32u + 31u)
                __hip_atomic_store(gen, (unsigned)(tt + 1), __ATOMIC_RELEASE, __HIP_MEMORY_SCOPE_AGENT);
        }
    }
}

__global__ void fc_kernel(const _Float16* __restrict__ h2, const float* __restrict__ Wfc,
                          const float* __restrict__ bfc, float* __restrict__ out) {
    int b = blockIdx.x;
    int lidx = threadIdx.x;
    float s = 0.f;
    #pragma unroll
    for (int h = lidx; h < H_; h += 64) s += (float)h2[b * H_ + h] * Wfc[h];
    #pragma unroll
    for (int off = 32; off; off >>= 1) s += __shfl_down(s, off);
    if (lidx == 0) out[b] = s + bfc[0];
}

extern "C" void kernel_launch(void* const* d_in, const int* in_sizes, int n_in,
                              void* d_out, int out_size, void* d_ws, size_t ws_size,
                              hipStream_t stream) {
    const float* x    = (const float*)d_in[0];
    const float* Wih0 = (const float*)d_in[1];
    const float* Whh0 = (const float*)d_in[2];
    const float* bih0 = (const float*)d_in[3];
    const float* bhh0 = (const float*)d_in[4];
    const float* Wih1 = (const float*)d_in[5];
    const float* Whh1 = (const float*)d_in[6];
    const float* bih1 = (const float*)d_in[7];
    const float* bhh1 = (const float*)d_in[8];
    const float* Wfc  = (const float*)d_in[9];
    const float* bfc  = (const float*)d_in[10];
    float* out = (float*)d_out;

    char* ws = (char*)d_ws;
    unsigned*  bar   = (unsigned*)ws;                       // 4 KB (8 groups x 256B)
    _Float16*  h1buf = (_Float16*)(ws + 4096);              // 2 x 256 KB
    _Float16*  h2buf = (_Float16*)(ws + 4096 + 524288);     // 2 x 256 KB
    _Float16*  Wp0   = (_Float16*)(ws + 4096 + 1048576);    // 2359296 B
    _Float16*  Wp1   = (_Float16*)(ws + 4096 + 1048576 + 2359296);  // 4194304 B

    hipMemsetAsync(d_ws, 0, 4096 + 1048576, stream);   // barriers + h parity buffers
    pack_w<NKS0, I_><<<4608, 256, 0, stream>>>(Wih0, Whh0, Wp0);
    pack_w<NKS1, H_><<<8192, 256, 0, stream>>>(Wih1, Whh1, Wp1);

    lstm_persistent<<<dim3(256), dim3(512), 0, stream>>>(
        x, Wp0, Wp1, bih0, bhh0, bih1, bhh1, h1buf, h2buf, bar);

    fc_kernel<<<B_, 64, 0, stream>>>(h2buf + BH, Wfc, bfc, out);
}

// Round 6
// 9626.907 us; speedup vs baseline: 1.2124x; 1.2124x over previous
//
#include <hip/hip_runtime.h>
#include <hip/hip_bf16.h>

typedef __attribute__((ext_vector_type(2))) _Float16 half2v;
typedef __attribute__((ext_vector_type(4))) _Float16 half4;
typedef __attribute__((ext_vector_type(8))) _Float16 half8;
typedef __attribute__((ext_vector_type(4))) float f32x4;
typedef __attribute__((ext_vector_type(2))) float f32x2;

#define T_ 512
#define B_ 256
#define I_ 64
#define H_ 512
#define BH (B_ * H_)
#define NKS0 36   // K = 64(x) + 512(h1)
#define NKS1 64   // K = 512(h1) + 512(h2)

// Wp[((cb*4+w)*NKS+ks)*256 + l*4 + i] = W[g = w*512 + cb*16 + (l&15)][k = ks*16 + (l>>4)*4 + i]
template<int NKS, int K0>
__global__ void pack_w(const float* __restrict__ Wih, const float* __restrict__ Whh,
                       _Float16* __restrict__ Wp) {
    int idx = blockIdx.x * 256 + threadIdx.x;
    int i  = idx & 3;
    int l  = (idx >> 2) & 63;
    int rest = idx >> 8;
    int ks = rest % NKS;
    int r  = rest / NKS;
    int w  = r & 3;
    int cb = r >> 2;
    int g  = w * H_ + cb * 16 + (l & 15);
    int k  = ks * 16 + ((l >> 4) << 2) + i;
    float v = (k < K0) ? Wih[(size_t)g * K0 + k] : Whh[(size_t)g * H_ + (k - K0)];
    Wp[idx] = (_Float16)v;
}

// ---- persistent LSTM: 256 blocks x 512 threads (1 block/CU by LDS).
// Block bid: group g=bid>>5 (32 batch rows), col-block cb=bid&31 (16 hidden cols).
// Waves 0-3: layer0 gates i,f,g,o. Waves 4-7: layer1 gates. Shared staged tile.
// Iteration tt: layer0 computes h1[tt] (tt<T), layer1 computes h2[tt-1] (tt>=1).
// Sync: per-block flag on its own 256B line; wave0 lanes poll all 32 group flags.
__global__ __launch_bounds__(512, 1) void lstm_persistent(
    const float* __restrict__ x,
    const _Float16* __restrict__ Wp0, const _Float16* __restrict__ Wp1,
    const float* __restrict__ bih0, const float* __restrict__ bhh0,
    const float* __restrict__ bih1, const float* __restrict__ bhh1,
    _Float16* __restrict__ h1buf, _Float16* __restrict__ h2buf,
    unsigned* __restrict__ bar)
{
    const int bid = blockIdx.x;
    const int g = bid >> 5, cb = bid & 31;
    const int tid = threadIdx.x;
    const int w = tid >> 6, l = tid & 63;
    const int lr = l & 15, lk = l >> 4;
    const int R0 = g * 32, c0 = cb * 16;
    const int sw = (lr & 7) << 4;          // XOR swizzle granule for tile reads

    __shared__ __attribute__((aligned(16))) char smem[65536 + 2 * 9216];
    float* gA = (float*)(smem + 65536);          // [4][32][18]
    float* gB = gA + 4 * 32 * 18;

    unsigned* myflag   = bar + (size_t)bid * 64;        // own 256B line
    unsigned* grpflags = bar + (size_t)(g * 32) * 64;   // group base

    const int er = (tid >> 3) & 31;     // epilogue row 0..31
    const int ec = (tid & 7) << 1;      // epilogue col 0,2..14
    const bool lay1 = tid >= 256;

    // bias for this thread's epilogue slice
    float br[4][2];
    {
        const float* bi = lay1 ? bih1 : bih0;
        const float* bh = lay1 ? bhh1 : bhh0;
        #pragma unroll
        for (int q = 0; q < 4; ++q)
            #pragma unroll
            for (int cc = 0; cc < 2; ++cc) {
                int gc = q * H_ + c0 + ec + cc;
                br[q][cc] = bi[gc] + bh[gc];
            }
    }

    // resident weights — SINGLE array so register demand is max(36,64), not sum
    half4 breg[NKS1];
    if (w < 4) {
        const _Float16* wb = Wp0 + ((size_t)(cb * 4 + w) * NKS0) * 256 + l * 4;
        #pragma unroll
        for (int ks = 0; ks < NKS0; ++ks) breg[ks] = *(const half4*)(wb + ks * 256);
    } else {
        const _Float16* wb = Wp1 + ((size_t)(cb * 4 + (w - 4)) * NKS1) * 256 + l * 4;
        #pragma unroll
        for (int ks = 0; ks < NKS1; ++ks) breg[ks] = *(const half4*)(wb + ks * 256);
    }

    f32x2 cstr = {0.f, 0.f};   // c1 (tid<256) or c2 (tid>=256) for (er, ec..ec+1)

    for (int tt = 0; tt <= T_; ++tt) {
        // x prefetch for this step (layer0 waves; issued before the barrier wait)
        f32x4 xr0[4], xr1[4];
        if (w < 4 && tt < T_) {
            const float* xa = x + (size_t)(R0 + lr) * (T_ * I_) + tt * I_ + lk * 4;
            const float* xb = x + (size_t)(R0 + 16 + lr) * (T_ * I_) + tt * I_ + lk * 4;
            #pragma unroll
            for (int ks = 0; ks < 4; ++ks) {
                xr0[ks] = *(const f32x4*)(xa + ks * 16);
                xr1[ks] = *(const f32x4*)(xb + ks * 16);
            }
        }

        // ---- wait: all 32 group blocks finished step tt-1 (parallel flag poll) ----
        if (tt > 0) {
            if (w == 0) {
                const unsigned tgt = (unsigned)tt;
                while (true) {
                    unsigned v = __hip_atomic_load(grpflags + (l & 31) * 64,
                                                   __ATOMIC_RELAXED, __HIP_MEMORY_SCOPE_AGENT);
                    if (__all(v >= tgt)) break;
                    __builtin_amdgcn_s_sleep(2);
                }
                __builtin_amdgcn_fence(__ATOMIC_ACQUIRE, "agent");  // one L1/L2 inv per step
            }
        }
        __syncthreads();

        // ---- stage tile = [ h1[tt-1] | h2[tt-2] ] for our 32 rows, XOR-swizzled ----
        {
            const _Float16* h1p = h1buf + ((tt + 1) & 1) * BH;
            const _Float16* h2p = h2buf + (tt & 1) * BH;
            #pragma unroll
            for (int it = 0; it < 8; ++it) {
                int cch = tid + it * 512;
                int row = cch >> 7, gr = cch & 127;
                const _Float16* src = (gr < 64)
                    ? h1p + (size_t)(R0 + row) * H_ + (gr << 3)
                    : h2p + (size_t)(R0 + row) * H_ + ((gr - 64) << 3);
                *(half8*)(smem + row * 2048 + ((gr ^ (row & 7)) << 4)) = *(const half8*)src;
            }
        }
        __syncthreads();

        // ---- MFMA + gate exchange ----
        if (w < 4) {
            if (tt < T_) {
                f32x4 acc0 = {0.f,0.f,0.f,0.f}, acc1 = {0.f,0.f,0.f,0.f};
                #pragma unroll
                for (int ks = 0; ks < 4; ++ks) {
                    half4 a0 = {(_Float16)xr0[ks][0], (_Float16)xr0[ks][1], (_Float16)xr0[ks][2], (_Float16)xr0[ks][3]};
                    half4 a1 = {(_Float16)xr1[ks][0], (_Float16)xr1[ks][1], (_Float16)xr1[ks][2], (_Float16)xr1[ks][3]};
                    acc0 = __builtin_amdgcn_mfma_f32_16x16x16f16(a0, breg[ks], acc0, 0, 0, 0);
                    acc1 = __builtin_amdgcn_mfma_f32_16x16x16f16(a1, breg[ks], acc1, 0, 0, 0);
                }
                #pragma unroll
                for (int ks = 4; ks < NKS0; ++ks) {
                    int cbyte = (ks - 4) * 32 + lk * 8;
                    half4 a0 = *(const half4*)(smem + lr * 2048 + (cbyte ^ sw));
                    half4 a1 = *(const half4*)(smem + (lr + 16) * 2048 + (cbyte ^ sw));
                    acc0 = __builtin_amdgcn_mfma_f32_16x16x16f16(a0, breg[ks], acc0, 0, 0, 0);
                    acc1 = __builtin_amdgcn_mfma_f32_16x16x16f16(a1, breg[ks], acc1, 0, 0, 0);
                }
                float* gb = gA + w * 576;
                #pragma unroll
                for (int r = 0; r < 4; ++r) {
                    gb[(lk * 4 + r) * 18 + lr]        = acc0[r];
                    gb[(16 + lk * 4 + r) * 18 + lr]   = acc1[r];
                }
            }
        } else {
            if (tt >= 1) {
                f32x4 acc0 = {0.f,0.f,0.f,0.f}, acc1 = {0.f,0.f,0.f,0.f};
                #pragma unroll
                for (int ks = 0; ks < NKS1; ++ks) {
                    int cbyte = ks * 32 + lk * 8;
                    half4 a0 = *(const half4*)(smem + lr * 2048 + (cbyte ^ sw));
                    half4 a1 = *(const half4*)(smem + (lr + 16) * 2048 + (cbyte ^ sw));
                    acc0 = __builtin_amdgcn_mfma_f32_16x16x16f16(a0, breg[ks], acc0, 0, 0, 0);
                    acc1 = __builtin_amdgcn_mfma_f32_16x16x16f16(a1, breg[ks], acc1, 0, 0, 0);
                }
                float* gb = gB + (w - 4) * 576;
                #pragma unroll
                for (int r = 0; r < 4; ++r) {
                    gb[(lk * 4 + r) * 18 + lr]        = acc0[r];
                    gb[(16 + lk * 4 + r) * 18 + lr]   = acc1[r];
                }
            }
        }
        __syncthreads();

        // ---- LSTM cell epilogue + h store ----
        bool act = lay1 ? (tt >= 1) : (tt < T_);
        if (act) {
            const float* gb = lay1 ? gB : gA;
            f32x2 gv[4];
            #pragma unroll
            for (int q = 0; q < 4; ++q) gv[q] = *(const f32x2*)&gb[q * 576 + er * 18 + ec];
            half2v hv;
            #pragma unroll
            for (int cc = 0; cc < 2; ++cc) {
                float gi = gv[0][cc] + br[0][cc];
                float gf = gv[1][cc] + br[1][cc];
                float gg = gv[2][cc] + br[2][cc];
                float go = gv[3][cc] + br[3][cc];
                float si = 1.f / (1.f + __expf(-gi));
                float sf = 1.f / (1.f + __expf(-gf));
                float tg = tanhf(gg);
                float so = 1.f / (1.f + __expf(-go));
                float cn = sf * cstr[cc] + si * tg;
                cstr[cc] = cn;
                hv[cc] = (_Float16)(so * tanhf(cn));
            }
            _Float16* dst = lay1 ? (h2buf + ((tt + 1) & 1) * BH)   // h2[tt-1]
                                 : (h1buf + (tt & 1) * BH);        // h1[tt]
            *(half2v*)&dst[(size_t)(R0 + er) * H_ + c0 + ec] = hv;
        }
        __syncthreads();   // all waves' h stores vmcnt-retired before arrival

        // ---- arrival: release (writeback L2), then set own flag ----
        if (tt < T_ && tid == 0) {
            __builtin_amdgcn_fence(__ATOMIC_RELEASE, "agent");
            __hip_atomic_store(myflag, (unsigned)(tt + 1),
                               __ATOMIC_RELAXED, __HIP_MEMORY_SCOPE_AGENT);
        }
    }
}

__global__ void fc_kernel(const _Float16* __restrict__ h2, const float* __restrict__ Wfc,
                          const float* __restrict__ bfc, float* __restrict__ out) {
    int b = blockIdx.x;
    int lidx = threadIdx.x;
    float s = 0.f;
    #pragma unroll
    for (int h = lidx; h < H_; h += 64) s += (float)h2[b * H_ + h] * Wfc[h];
    #pragma unroll
    for (int off = 32; off; off >>= 1) s += __shfl_down(s, off);
    if (lidx == 0) out[b] = s + bfc[0];
}

extern "C" void kernel_launch(void* const* d_in, const int* in_sizes, int n_in,
                              void* d_out, int out_size, void* d_ws, size_t ws_size,
                              hipStream_t stream) {
    const float* x    = (const float*)d_in[0];
    const float* Wih0 = (const float*)d_in[1];
    const float* Whh0 = (const float*)d_in[2];
    const float* bih0 = (const float*)d_in[3];
    const float* bhh0 = (const float*)d_in[4];
    const float* Wih1 = (const float*)d_in[5];
    const float* Whh1 = (const float*)d_in[6];
    const float* bih1 = (const float*)d_in[7];
    const float* bhh1 = (const float*)d_in[8];
    const float* Wfc  = (const float*)d_in[9];
    const float* bfc  = (const float*)d_in[10];
    float* out = (float*)d_out;

    char* ws = (char*)d_ws;
    unsigned*  bar   = (unsigned*)ws;                        // 64 KB: 256 flags x 256B
    _Float16*  h1buf = (_Float16*)(ws + 65536);              // 2 x 256 KB
    _Float16*  h2buf = (_Float16*)(ws + 65536 + 524288);     // 2 x 256 KB
    _Float16*  Wp0   = (_Float16*)(ws + 65536 + 1048576);    // 2359296 B
    _Float16*  Wp1   = (_Float16*)(ws + 65536 + 1048576 + 2359296);  // 4194304 B

    hipMemsetAsync(d_ws, 0, 65536 + 1048576, stream);   // flags + h parity buffers
    pack_w<NKS0, I_><<<4608, 256, 0, stream>>>(Wih0, Whh0, Wp0);
    pack_w<NKS1, H_><<<8192, 256, 0, stream>>>(Wih1, Whh1, Wp1);

    lstm_persistent<<<dim3(256), dim3(512), 0, stream>>>(
        x, Wp0, Wp1, bih0, bhh0, bih1, bhh1, h1buf, h2buf, bar);

    fc_kernel<<<B_, 64, 0, stream>>>(h2buf + BH, Wfc, bfc, out);
}

// Round 7
// 7241.238 us; speedup vs baseline: 1.6118x; 1.3295x over previous
//
#include <hip/hip_runtime.h>
#include <hip/hip_bf16.h>

typedef __attribute__((ext_vector_type(2))) _Float16 half2v;
typedef __attribute__((ext_vector_type(4))) _Float16 half4;
typedef __attribute__((ext_vector_type(8))) _Float16 half8;
typedef __attribute__((ext_vector_type(4))) float f32x4;
typedef __attribute__((ext_vector_type(2))) float f32x2;

#define T_ 512
#define B_ 256
#define I_ 64
#define H_ 512
#define BH (B_ * H_)
#define NKS0 36   // K = 64(x) + 512(h1)
#define NKS1 64   // K = 512(h1) + 512(h2)

// Wp[((cb*4+w)*NKS+ks)*256 + l*4 + i] = W[g = w*512 + cb*16 + (l&15)][k = ks*16 + (l>>4)*4 + i]
template<int NKS, int K0>
__global__ void pack_w(const float* __restrict__ Wih, const float* __restrict__ Whh,
                       _Float16* __restrict__ Wp) {
    int idx = blockIdx.x * 256 + threadIdx.x;
    int i  = idx & 3;
    int l  = (idx >> 2) & 63;
    int rest = idx >> 8;
    int ks = rest % NKS;
    int r  = rest / NKS;
    int w  = r & 3;
    int cb = r >> 2;
    int g  = w * H_ + cb * 16 + (l & 15);
    int k  = ks * 16 + ((l >> 4) << 2) + i;
    float v = (k < K0) ? Wih[(size_t)g * K0 + k] : Whh[(size_t)g * H_ + (k - K0)];
    Wp[idx] = (_Float16)v;
}

// ---- persistent LSTM: 256 blocks x 512 threads (1 block/CU by LDS).
// Block bid: group g=bid>>5 (32 batch rows), col-block cb=bid&31 (16 hidden cols).
// Waves 0-3: layer0 gates i,f,g,o. Waves 4-7: layer1 gates. Shared staged tile.
// Iteration tt: layer0 computes h1[tt] (tt<T), layer1 computes h2[tt-1] (tt>=1).
// Coherence: h exchanged via agent-scope atomic (cache-bypassing) stores/loads;
// flags set after __syncthreads vmcnt-drain. NO cache-wide fences in the loop.
__global__ __launch_bounds__(512, 1) void lstm_persistent(
    const float* __restrict__ x,
    const _Float16* __restrict__ Wp0, const _Float16* __restrict__ Wp1,
    const float* __restrict__ bih0, const float* __restrict__ bhh0,
    const float* __restrict__ bih1, const float* __restrict__ bhh1,
    _Float16* __restrict__ h1buf, _Float16* __restrict__ h2buf,
    unsigned* __restrict__ bar)
{
    const int bid = blockIdx.x;
    const int g = bid >> 5, cb = bid & 31;
    const int tid = threadIdx.x;
    const int w = tid >> 6, l = tid & 63;
    const int lr = l & 15, lk = l >> 4;
    const int R0 = g * 32, c0 = cb * 16;
    const int sw = (lr & 7) << 4;          // XOR swizzle granule (16B units) for tile reads

    __shared__ __attribute__((aligned(16))) char smem[65536 + 2 * 9216];
    float* gA = (float*)(smem + 65536);          // [4][32][18]
    float* gB = gA + 4 * 32 * 18;

    unsigned* myflag   = bar + (size_t)bid * 64;        // own 256B line
    unsigned* grpflags = bar + (size_t)(g * 32) * 64;   // group base

    const int er = (tid >> 3) & 31;     // epilogue row 0..31
    const int ec = (tid & 7) << 1;      // epilogue col 0,2..14
    const bool lay1 = tid >= 256;

    float br[4][2];
    {
        const float* bi = lay1 ? bih1 : bih0;
        const float* bh = lay1 ? bhh1 : bhh0;
        #pragma unroll
        for (int q = 0; q < 4; ++q)
            #pragma unroll
            for (int cc = 0; cc < 2; ++cc) {
                int gc = q * H_ + c0 + ec + cc;
                br[q][cc] = bi[gc] + bh[gc];
            }
    }

    // resident weights — SINGLE array so register demand is max(36,64), not sum
    half4 breg[NKS1];
    if (w < 4) {
        const _Float16* wb = Wp0 + ((size_t)(cb * 4 + w) * NKS0) * 256 + l * 4;
        #pragma unroll
        for (int ks = 0; ks < NKS0; ++ks) breg[ks] = *(const half4*)(wb + ks * 256);
    } else {
        const _Float16* wb = Wp1 + ((size_t)(cb * 4 + (w - 4)) * NKS1) * 256 + l * 4;
        #pragma unroll
        for (int ks = 0; ks < NKS1; ++ks) breg[ks] = *(const half4*)(wb + ks * 256);
    }

    f32x2 cstr = {0.f, 0.f};   // c1 (tid<256) or c2 (tid>=256) for (er, ec..ec+1)

    for (int tt = 0; tt <= T_; ++tt) {
        // x prefetch for this step (layer0 waves; issued before the barrier wait; L2-warm)
        f32x4 xr0[4], xr1[4];
        if (w < 4 && tt < T_) {
            const float* xa = x + (size_t)(R0 + lr) * (T_ * I_) + tt * I_ + lk * 4;
            const float* xb = x + (size_t)(R0 + 16 + lr) * (T_ * I_) + tt * I_ + lk * 4;
            #pragma unroll
            for (int ks = 0; ks < 4; ++ks) {
                xr0[ks] = *(const f32x4*)(xa + ks * 16);
                xr1[ks] = *(const f32x4*)(xb + ks * 16);
            }
        }

        // ---- wait: all 32 group blocks finished step tt-1 (parallel flag poll, no fence) ----
        if (tt > 0) {
            if (w == 0) {
                const unsigned tgt = (unsigned)tt;
                while (true) {
                    unsigned v = __hip_atomic_load(grpflags + (l & 31) * 64,
                                                   __ATOMIC_RELAXED, __HIP_MEMORY_SCOPE_AGENT);
                    if (__all(v >= tgt)) break;
                    __builtin_amdgcn_s_sleep(2);
                }
            }
        }
        __syncthreads();

        // ---- stage tile = [ h1[tt-1] | h2[tt-2] ] via cache-bypassing u64 loads ----
        {
            const _Float16* h1p = h1buf + ((tt + 1) & 1) * BH;
            const _Float16* h2p = h2buf + (tt & 1) * BH;
            unsigned long long tmp[16];
            #pragma unroll
            for (int it = 0; it < 16; ++it) {
                int cch = tid + it * 512;        // 0..8191 (8B granules)
                int row = cch >> 8;              // 0..31
                int gr8 = cch & 255;             // 8B granule within 2KB row
                const _Float16* src = (gr8 < 128)
                    ? h1p + (size_t)(R0 + row) * H_ + (gr8 << 2)
                    : h2p + (size_t)(R0 + row) * H_ + ((gr8 - 128) << 2);
                tmp[it] = __hip_atomic_load((const unsigned long long*)src,
                                            __ATOMIC_RELAXED, __HIP_MEMORY_SCOPE_AGENT);
            }
            #pragma unroll
            for (int it = 0; it < 16; ++it) {
                int cch = tid + it * 512;
                int row = cch >> 8, gr8 = cch & 255;
                *(unsigned long long*)(smem + row * 2048 +
                                       ((gr8 ^ ((row & 7) << 1)) << 3)) = tmp[it];
            }
        }
        __syncthreads();

        // ---- MFMA + gate exchange ----
        if (w < 4) {
            if (tt < T_) {
                f32x4 acc0 = {0.f,0.f,0.f,0.f}, acc1 = {0.f,0.f,0.f,0.f};
                #pragma unroll
                for (int ks = 0; ks < 4; ++ks) {
                    half4 a0 = {(_Float16)xr0[ks][0], (_Float16)xr0[ks][1], (_Float16)xr0[ks][2], (_Float16)xr0[ks][3]};
                    half4 a1 = {(_Float16)xr1[ks][0], (_Float16)xr1[ks][1], (_Float16)xr1[ks][2], (_Float16)xr1[ks][3]};
                    acc0 = __builtin_amdgcn_mfma_f32_16x16x16f16(a0, breg[ks], acc0, 0, 0, 0);
                    acc1 = __builtin_amdgcn_mfma_f32_16x16x16f16(a1, breg[ks], acc1, 0, 0, 0);
                }
                #pragma unroll
                for (int ks = 4; ks < NKS0; ++ks) {
                    int cbyte = (ks - 4) * 32 + lk * 8;
                    half4 a0 = *(const half4*)(smem + lr * 2048 + (cbyte ^ sw));
                    half4 a1 = *(const half4*)(smem + (lr + 16) * 2048 + (cbyte ^ sw));
                    acc0 = __builtin_amdgcn_mfma_f32_16x16x16f16(a0, breg[ks], acc0, 0, 0, 0);
                    acc1 = __builtin_amdgcn_mfma_f32_16x16x16f16(a1, breg[ks], acc1, 0, 0, 0);
                }
                float* gb = gA + w * 576;
                #pragma unroll
                for (int r = 0; r < 4; ++r) {
                    gb[(lk * 4 + r) * 18 + lr]        = acc0[r];
                    gb[(16 + lk * 4 + r) * 18 + lr]   = acc1[r];
                }
            }
        } else {
            if (tt >= 1) {
                f32x4 acc0 = {0.f,0.f,0.f,0.f}, acc1 = {0.f,0.f,0.f,0.f};
                #pragma unroll
                for (int ks = 0; ks < NKS1; ++ks) {
                    int cbyte = ks * 32 + lk * 8;
                    half4 a0 = *(const half4*)(smem + lr * 2048 + (cbyte ^ sw));
                    half4 a1 = *(const half4*)(smem + (lr + 16) * 2048 + (cbyte ^ sw));
                    acc0 = __builtin_amdgcn_mfma_f32_16x16x16f16(a0, breg[ks], acc0, 0, 0, 0);
                    acc1 = __builtin_amdgcn_mfma_f32_16x16x16f16(a1, breg[ks], acc1, 0, 0, 0);
                }
                float* gb = gB + (w - 4) * 576;
                #pragma unroll
                for (int r = 0; r < 4; ++r) {
                    gb[(lk * 4 + r) * 18 + lr]        = acc0[r];
                    gb[(16 + lk * 4 + r) * 18 + lr]   = acc1[r];
                }
            }
        }
        __syncthreads();

        // ---- LSTM cell epilogue + write-through h store ----
        bool act = lay1 ? (tt >= 1) : (tt < T_);
        if (act) {
            const float* gb = lay1 ? gB : gA;
            f32x2 gv[4];
            #pragma unroll
            for (int q = 0; q < 4; ++q) gv[q] = *(const f32x2*)&gb[q * 576 + er * 18 + ec];
            half2v hv;
            #pragma unroll
            for (int cc = 0; cc < 2; ++cc) {
                float gi = gv[0][cc] + br[0][cc];
                float gf = gv[1][cc] + br[1][cc];
                float gg = gv[2][cc] + br[2][cc];
                float go = gv[3][cc] + br[3][cc];
                float si = 1.f / (1.f + __expf(-gi));
                float sf = 1.f / (1.f + __expf(-gf));
                float tg = tanhf(gg);
                float so = 1.f / (1.f + __expf(-go));
                float cn = sf * cstr[cc] + si * tg;
                cstr[cc] = cn;
                hv[cc] = (_Float16)(so * tanhf(cn));
            }
            _Float16* dst = lay1 ? (h2buf + ((tt + 1) & 1) * BH)   // h2[tt-1]
                                 : (h1buf + (tt & 1) * BH);        // h1[tt]
            unsigned hbits = __builtin_bit_cast(unsigned, hv);
            __hip_atomic_store((unsigned*)&dst[(size_t)(R0 + er) * H_ + c0 + ec], hbits,
                               __ATOMIC_RELAXED, __HIP_MEMORY_SCOPE_AGENT);
        }
        __syncthreads();   // drains vmcnt: h stores ack'd at coherent point

        // ---- arrival: flag store (h already globally visible) ----
        if (tt < T_ && tid == 0) {
            __hip_atomic_store(myflag, (unsigned)(tt + 1),
                               __ATOMIC_RELAXED, __HIP_MEMORY_SCOPE_AGENT);
        }
    }
}

__global__ void fc_kernel(const _Float16* __restrict__ h2, const float* __restrict__ Wfc,
                          const float* __restrict__ bfc, float* __restrict__ out) {
    int b = blockIdx.x;
    int lidx = threadIdx.x;
    float s = 0.f;
    #pragma unroll
    for (int h = lidx; h < H_; h += 64) s += (float)h2[b * H_ + h] * Wfc[h];
    #pragma unroll
    for (int off = 32; off; off >>= 1) s += __shfl_down(s, off);
    if (lidx == 0) out[b] = s + bfc[0];
}

extern "C" void kernel_launch(void* const* d_in, const int* in_sizes, int n_in,
                              void* d_out, int out_size, void* d_ws, size_t ws_size,
                              hipStream_t stream) {
    const float* x    = (const float*)d_in[0];
    const float* Wih0 = (const float*)d_in[1];
    const float* Whh0 = (const float*)d_in[2];
    const float* bih0 = (const float*)d_in[3];
    const float* bhh0 = (const float*)d_in[4];
    const float* Wih1 = (const float*)d_in[5];
    const float* Whh1 = (const float*)d_in[6];
    const float* bih1 = (const float*)d_in[7];
    const float* bhh1 = (const float*)d_in[8];
    const float* Wfc  = (const float*)d_in[9];
    const float* bfc  = (const float*)d_in[10];
    float* out = (float*)d_out;

    char* ws = (char*)d_ws;
    unsigned*  bar   = (unsigned*)ws;                        // 64 KB: 256 flags x 256B
    _Float16*  h1buf = (_Float16*)(ws + 65536);              // 2 x 256 KB
    _Float16*  h2buf = (_Float16*)(ws + 65536 + 524288);     // 2 x 256 KB
    _Float16*  Wp0   = (_Float16*)(ws + 65536 + 1048576);    // 2359296 B
    _Float16*  Wp1   = (_Float16*)(ws + 65536 + 1048576 + 2359296);  // 4194304 B

    hipMemsetAsync(d_ws, 0, 65536 + 1048576, stream);   // flags + h parity buffers
    pack_w<NKS0, I_><<<4608, 256, 0, stream>>>(Wih0, Whh0, Wp0);
    pack_w<NKS1, H_><<<8192, 256, 0, stream>>>(Wih1, Whh1, Wp1);

    lstm_persistent<<<dim3(256), dim3(512), 0, stream>>>(
        x, Wp0, Wp1, bih0, bhh0, bih1, bhh1, h1buf, h2buf, bar);

    fc_kernel<<<B_, 64, 0, stream>>>(h2buf + BH, Wfc, bfc, out);
}

// Round 9
// 4632.463 us; speedup vs baseline: 2.5195x; 1.5632x over previous
//
#include <hip/hip_runtime.h>
#include <hip/hip_bf16.h>

typedef __attribute__((ext_vector_type(2))) _Float16 half2v;
typedef __attribute__((ext_vector_type(4))) _Float16 half4;
typedef __attribute__((ext_vector_type(4))) float f32x4;
typedef __attribute__((ext_vector_type(2))) float f32x2;

#define T_ 512
#define B_ 256
#define I_ 64
#define H_ 512
#define BH (B_ * H_)
#define NKS0 36   // K = 64(x) + 512(h1)
#define NKS1 64   // K = 512(h1) + 512(h2)

// Wp[((cb*4+w)*NKS+ks)*256 + l*4 + i] = W[g = w*512 + cb*16 + (l&15)][k = ks*16 + (l>>4)*4 + i]
template<int NKS, int K0>
__global__ void pack_w(const float* __restrict__ Wih, const float* __restrict__ Whh,
                       _Float16* __restrict__ Wp) {
    int idx = blockIdx.x * 256 + threadIdx.x;
    int i  = idx & 3;
    int l  = (idx >> 2) & 63;
    int rest = idx >> 8;
    int ks = rest % NKS;
    int r  = rest / NKS;
    int w  = r & 3;
    int cb = r >> 2;
    int g  = w * H_ + cb * 16 + (l & 15);
    int k  = ks * 16 + ((l >> 4) << 2) + i;
    float v = (k < K0) ? Wih[(size_t)g * K0 + k] : Whh[(size_t)g * H_ + (k - K0)];
    Wp[idx] = (_Float16)v;
}

// ---- device-coherent (sc0 sc1) primitives — the ONLY HW-validated cross-block path ----
__device__ __forceinline__ unsigned fload(const unsigned* p) {
    unsigned v;
    asm volatile("global_load_dword %0, %1, off sc0 sc1\n\ts_waitcnt vmcnt(0)"
                 : "=&v"(v) : "v"(p) : "memory");
    return v;
}
__device__ __forceinline__ void fstore(unsigned* p, unsigned v) {
    asm volatile("global_store_dword %0, %1, off sc0 sc1" :: "v"(p), "v"(v) : "memory");
}
__device__ __forceinline__ void fstore16(void* p, f32x4 v) {
    asm volatile("global_store_dwordx4 %0, %1, off sc0 sc1" :: "v"(p), "v"(v) : "memory");
}
__device__ __forceinline__ f32x4 gload16(const void* p) {
    f32x4 v;
    asm volatile("global_load_dwordx4 %0, %1, off sc0 sc1" : "=&v"(v) : "v"(p) : "memory");
    return v;
}

// ---- persistent LSTM: 256 blocks x 512 threads (1 block/CU by LDS).
// Block bid: group g=bid>>5 (32 batch rows), col-block cb=bid&31 (16 hidden cols).
// Waves 0-3: layer0 gates i,f,g,o. Waves 4-7: layer1 gates. Shared staged tile.
// Iteration tt: layer0 computes h1[tt] (tt<T), layer1 computes h2[tt-1] (tt>=1).
// Sync: per-group flag line (32 dwords, one 128B line) at the coherent point;
// poll = ONE coalesced request/iter. h exchange via sc0 sc1 bypass ops.
__global__ __launch_bounds__(512, 1) void lstm_persistent(
    const float* __restrict__ x,
    const _Float16* __restrict__ Wp0, const _Float16* __restrict__ Wp1,
    const float* __restrict__ bih0, const float* __restrict__ bhh0,
    const float* __restrict__ bih1, const float* __restrict__ bhh1,
    _Float16* __restrict__ h1buf, _Float16* __restrict__ h2buf,
    unsigned* __restrict__ bar)
{
    const int bid = blockIdx.x;
    const int g = bid >> 5, cb = bid & 31;
    const int tid = threadIdx.x;
    const int w = tid >> 6, l = tid & 63;
    const int lr = l & 15, lk = l >> 4;
    const int R0 = g * 32, c0 = cb * 16;
    const int xsw = lr << 4;            // read-side XOR (16B granule), rows lr / lr+16 share it

    __shared__ __attribute__((aligned(16))) char smem[65536 + 2 * 9216 + 2048];
    float* gA = (float*)(smem + 65536);             // [4][32][18] layer0 gate exchange
    float* gB = (float*)(smem + 65536 + 9216);      // [4][32][18] layer1
    _Float16* hbuf = (_Float16*)(smem + 83968);     // [2][32][16] h staging for coalesced store

    unsigned* grpline = bar + (size_t)g * 64;       // 32 flags in one 128B line (256B spacing)
    unsigned* myflag  = grpline + cb;

    const int er = (tid >> 3) & 31;
    const int ec = (tid & 7) << 1;
    const bool lay1 = tid >= 256;

    float br[4][2];
    {
        const float* bi = lay1 ? bih1 : bih0;
        const float* bh = lay1 ? bhh1 : bhh0;
        #pragma unroll
        for (int q = 0; q < 4; ++q)
            #pragma unroll
            for (int cc = 0; cc < 2; ++cc) {
                int gc = q * H_ + c0 + ec + cc;
                br[q][cc] = bi[gc] + bh[gc];
            }
    }

    // resident weights — single array: demand = max(36,64) regs, not sum
    half4 breg[NKS1];
    if (w < 4) {
        const _Float16* wb = Wp0 + ((size_t)(cb * 4 + w) * NKS0) * 256 + l * 4;
        #pragma unroll
        for (int ks = 0; ks < NKS0; ++ks) breg[ks] = *(const half4*)(wb + ks * 256);
    } else {
        const _Float16* wb = Wp1 + ((size_t)(cb * 4 + (w - 4)) * NKS1) * 256 + l * 4;
        #pragma unroll
        for (int ks = 0; ks < NKS1; ++ks) breg[ks] = *(const half4*)(wb + ks * 256);
    }

    f32x2 cstr = {0.f, 0.f};

    for (int tt = 0; tt <= T_; ++tt) {
        // x prefetch (plain cached loads, immutable data)
        f32x4 xr0[4], xr1[4];
        if (w < 4 && tt < T_) {
            const float* xa = x + (size_t)(R0 + lr) * (T_ * I_) + tt * I_ + lk * 4;
            const float* xb = x + (size_t)(R0 + 16 + lr) * (T_ * I_) + tt * I_ + lk * 4;
            #pragma unroll
            for (int ks = 0; ks < 4; ++ks) {
                xr0[ks] = *(const f32x4*)(xa + ks * 16);
                xr1[ks] = *(const f32x4*)(xb + ks * 16);
            }
        }

        // ---- wait: all 32 group blocks finished step tt-1 (ONE coalesced poll request) ----
        if (tt > 0 && w == 0) {
            const unsigned tgt = (unsigned)tt;
            while (true) {
                unsigned v = fload(grpline + (l & 31));
                if (__all(v >= tgt)) break;
                __builtin_amdgcn_s_sleep(4);
            }
        }
        __syncthreads();

        // ---- stage tile = [ h1[tt-1] | h2[tt-2] ], swizzled g16 ^= row&15 ----
        {
            const _Float16* h1p = h1buf + ((tt + 1) & 1) * BH;
            const _Float16* h2p = h2buf + (tt & 1) * BH;
            f32x4 t[8];
            #pragma unroll
            for (int it = 0; it < 8; ++it) {
                int cch = tid + it * 512;          // 16B granules, 4096 total
                int row = cch >> 7, g16 = cch & 127;
                const _Float16* src = (g16 < 64)
                    ? h1p + (size_t)(R0 + row) * H_ + (g16 << 3)
                    : h2p + (size_t)(R0 + row) * H_ + ((g16 - 64) << 3);
                t[it] = gload16(src);
            }
            asm volatile("s_waitcnt vmcnt(0)" ::: "memory");
            __builtin_amdgcn_sched_barrier(0);
            #pragma unroll
            for (int it = 0; it < 8; ++it) {
                int cch = tid + it * 512;
                int row = cch >> 7, g16 = cch & 127;
                *(f32x4*)(smem + row * 2048 + ((g16 ^ (row & 15)) << 4)) = t[it];
            }
        }
        __syncthreads();

        // ---- MFMA + gate exchange ----
        if (w < 4) {
            if (tt < T_) {
                f32x4 acc0 = {0.f,0.f,0.f,0.f}, acc1 = {0.f,0.f,0.f,0.f};
                #pragma unroll
                for (int ks = 0; ks < 4; ++ks) {
                    half4 a0 = {(_Float16)xr0[ks][0], (_Float16)xr0[ks][1], (_Float16)xr0[ks][2], (_Float16)xr0[ks][3]};
                    half4 a1 = {(_Float16)xr1[ks][0], (_Float16)xr1[ks][1], (_Float16)xr1[ks][2], (_Float16)xr1[ks][3]};
                    acc0 = __builtin_amdgcn_mfma_f32_16x16x16f16(a0, breg[ks], acc0, 0, 0, 0);
                    acc1 = __builtin_amdgcn_mfma_f32_16x16x16f16(a1, breg[ks], acc1, 0, 0, 0);
                }
                #pragma unroll
                for (int ks = 4; ks < NKS0; ++ks) {
                    int cbyte = ((ks - 4) * 32 + lk * 8) ^ xsw;
                    half4 a0 = *(const half4*)(smem + lr * 2048 + cbyte);
                    half4 a1 = *(const half4*)(smem + (lr + 16) * 2048 + cbyte);
                    acc0 = __builtin_amdgcn_mfma_f32_16x16x16f16(a0, breg[ks], acc0, 0, 0, 0);
                    acc1 = __builtin_amdgcn_mfma_f32_16x16x16f16(a1, breg[ks], acc1, 0, 0, 0);
                }
                float* gb = gA + w * 576;
                #pragma unroll
                for (int r = 0; r < 4; ++r) {
                    gb[(lk * 4 + r) * 18 + lr]      = acc0[r];
                    gb[(16 + lk * 4 + r) * 18 + lr] = acc1[r];
                }
            }
        } else {
            if (tt >= 1) {
                f32x4 acc0 = {0.f,0.f,0.f,0.f}, acc1 = {0.f,0.f,0.f,0.f};
                #pragma unroll
                for (int ks = 0; ks < NKS1; ++ks) {
                    int cbyte = (ks * 32 + lk * 8) ^ xsw;
                    half4 a0 = *(const half4*)(smem + lr * 2048 + cbyte);
                    half4 a1 = *(const half4*)(smem + (lr + 16) * 2048 + cbyte);
                    acc0 = __builtin_amdgcn_mfma_f32_16x16x16f16(a0, breg[ks], acc0, 0, 0, 0);
                    acc1 = __builtin_amdgcn_mfma_f32_16x16x16f16(a1, breg[ks], acc1, 0, 0, 0);
                }
                float* gb = gB + (w - 4) * 576;
                #pragma unroll
                for (int r = 0; r < 4; ++r) {
                    gb[(lk * 4 + r) * 18 + lr]      = acc0[r];
                    gb[(16 + lk * 4 + r) * 18 + lr] = acc1[r];
                }
            }
        }
        __syncthreads();

        // ---- LSTM cell epilogue -> LDS hbuf (no global store yet) ----
        {
            const float* gb = lay1 ? gB : gA;
            f32x2 gv[4];
            #pragma unroll
            for (int q = 0; q < 4; ++q) gv[q] = *(const f32x2*)&gb[q * 576 + er * 18 + ec];
            half2v hv;
            #pragma unroll
            for (int cc = 0; cc < 2; ++cc) {
                float gi = gv[0][cc] + br[0][cc];
                float gf = gv[1][cc] + br[1][cc];
                float gg = gv[2][cc] + br[2][cc];
                float go = gv[3][cc] + br[3][cc];
                float si = 1.f / (1.f + __expf(-gi));
                float sf = 1.f / (1.f + __expf(-gf));
                float tg = tanhf(gg);
                float so = 1.f / (1.f + __expf(-go));
                float cn = sf * cstr[cc] + si * tg;
                bool act = lay1 ? (tt >= 1) : (tt < T_);
                if (act) cstr[cc] = cn;
                float th = tanhf(cn);
                hv[cc] = (_Float16)(so * th);
            }
            *(half2v*)&hbuf[(lay1 ? 512 : 0) + er * 16 + ec] = hv;
        }
        __syncthreads();

        // ---- coalesced 16B h stores (threads 0-127) ----
        if (tid < 128) {
            int layer = tid >> 6;
            int row = (tid & 63) >> 1, chunk = tid & 1;
            bool act = layer ? (tt >= 1) : (tt < T_);
            if (act) {
                f32x4 v = *(const f32x4*)&hbuf[layer * 512 + row * 16 + chunk * 8];
                _Float16* dst = layer
                    ? (h2buf + ((tt + 1) & 1) * BH)   // h2[tt-1]
                    : (h1buf + (tt & 1) * BH);        // h1[tt]
                fstore16(&dst[(size_t)(R0 + row) * H_ + c0 + chunk * 8], v);
            }
        }
        asm volatile("s_waitcnt vmcnt(0)" ::: "memory");   // h stores ack'd at coherent pt
        __syncthreads();

        // ---- arrival flag (h already globally visible) ----
        if (tt < T_ && tid == 0) fstore(myflag, (unsigned)(tt + 1));
    }
}

__global__ void fc_kernel(const _Float16* __restrict__ h2, const float* __restrict__ Wfc,
                          const float* __restrict__ bfc, float* __restrict__ out) {
    int b = blockIdx.x;
    int lidx = threadIdx.x;
    float s = 0.f;
    #pragma unroll
    for (int h = lidx; h < H_; h += 64) s += (float)h2[b * H_ + h] * Wfc[h];
    #pragma unroll
    for (int off = 32; off; off >>= 1) s += __shfl_down(s, off);
    if (lidx == 0) out[b] = s + bfc[0];
}

extern "C" void kernel_launch(void* const* d_in, const int* in_sizes, int n_in,
                              void* d_out, int out_size, void* d_ws, size_t ws_size,
                              hipStream_t stream) {
    const float* x    = (const float*)d_in[0];
    const float* Wih0 = (const float*)d_in[1];
    const float* Whh0 = (const float*)d_in[2];
    const float* bih0 = (const float*)d_in[3];
    const float* bhh0 = (const float*)d_in[4];
    const float* Wih1 = (const float*)d_in[5];
    const float* Whh1 = (const float*)d_in[6];
    const float* bih1 = (const float*)d_in[7];
    const float* bhh1 = (const float*)d_in[8];
    const float* Wfc  = (const float*)d_in[9];
    const float* bfc  = (const float*)d_in[10];
    float* out = (float*)d_out;

    char* ws = (char*)d_ws;
    unsigned*  bar   = (unsigned*)ws;                       // 4 KB: 8 group flag-lines (256B apart)
    _Float16*  h1buf = (_Float16*)(ws + 4096);              // 2 x 256 KB
    _Float16*  h2buf = (_Float16*)(ws + 4096 + 524288);     // 2 x 256 KB
    _Float16*  Wp0   = (_Float16*)(ws + 4096 + 1048576);    // 2359296 B
    _Float16*  Wp1   = (_Float16*)(ws + 4096 + 1048576 + 2359296);  // 4194304 B

    hipMemsetAsync(d_ws, 0, 4096 + 1048576, stream);   // flags + h parity buffers
    pack_w<NKS0, I_><<<4608, 256, 0, stream>>>(Wih0, Whh0, Wp0);
    pack_w<NKS1, H_><<<8192, 256, 0, stream>>>(Wih1, Whh1, Wp1);

    lstm_persistent<<<dim3(256), dim3(512), 0, stream>>>(
        x, Wp0, Wp1, bih0, bhh0, bih1, bhh1, h1buf, h2buf, bar);

    fc_kernel<<<B_, 64, 0, stream>>>(h2buf + BH, Wfc, bfc, out);
}